// Round 11
// baseline (637.864 us; speedup 1.0000x reference)
//
#include <hip/hip_runtime.h>
#include <stdint.h>

#define NND 50000
#define NED 800000
#define CH  128
#define NCHUNK 782   // ceil(NND/64)

typedef unsigned short us;
typedef unsigned int u32;
using bf16x8 = __attribute__((ext_vector_type(8))) __bf16;
using f32x4  = __attribute__((ext_vector_type(4))) float;

static __device__ __forceinline__ us f2bfu(float f){
  __bf16 b = (__bf16)f;
  return __builtin_bit_cast(us, b);
}
static __device__ __forceinline__ float silu_f(float x){
  return __fdividef(x, 1.0f + __expf(-x));
}
static __device__ __forceinline__ f32x4 mfma16(bf16x8 a, bf16x8 b, f32x4 c){
  return __builtin_amdgcn_mfma_f32_16x16x32_bf16(a, b, c, 0, 0, 0);
}
static __device__ __forceinline__ bf16x8 ldb8(const us* p){
  return *reinterpret_cast<const bf16x8*>(p);
}
static __device__ __forceinline__ float gelu_f(float x){
  return 0.5f*x*(1.0f + erff(x*0.70710678118654752f));
}

// ---------------- weight prep: transpose + bf16 cast ----------------
__global__ void prep_kernel(const float* __restrict__ We1, const float* __restrict__ We2,
                            const float* __restrict__ Wn1, const float* __restrict__ Wn2,
                            const float* __restrict__ Wi1, const float* __restrict__ Wi2,
                            us* __restrict__ We1T, us* __restrict__ We2T,
                            us* __restrict__ Wn1T, us* __restrict__ Wn2T,
                            us* __restrict__ Wi1T, us* __restrict__ Wi2T,
                            float* __restrict__ rw)
{
  int i = blockIdx.x * 256 + threadIdx.x;   // 0..65535
  {
    int l = i >> 15, j = (i >> 8) & 127, k = i & 255;
    We1T[i] = f2bfu(We1[(l*257 + k)*128 + j]);
    Wn1T[i] = f2bfu(Wn1[(l*256 + k)*128 + j]);
  }
  if (i < 32768) {
    int l = i >> 14, j = (i >> 7) & 127, k = i & 127;
    We2T[i] = f2bfu(We2[(l*128 + k)*128 + j]);
    Wn2T[i] = f2bfu(Wn2[(l*128 + k)*128 + j]);
  }
  if (i < 8192) {
    int j = i >> 6, k = i & 63;
    Wi1T[i] = f2bfu(Wi1[k*128 + j]);
  }
  if (i < 16384) {
    int j = i >> 7, k = i & 127;
    Wi2T[i] = f2bfu(Wi2[k*128 + j]);
  }
  if (i < 256) {
    int l = i >> 7, j = i & 127;
    rw[i] = We1[(l*257 + 256)*128 + j];
  }
}

// ---------------- counting sort by dst ----------------
__global__ void hist_kernel(const int* __restrict__ dst, u32* __restrict__ counts)
{
  int e = blockIdx.x * 256 + threadIdx.x;
  if (e < NED) atomicAdd(&counts[dst[e]], 1u);
}

// ---- parallel scan: stage 1 — per-64-chunk sums (wave per chunk) ----
__global__ void scan_part_kernel(const u32* __restrict__ counts, u32* __restrict__ partial)
{
  const int w = blockIdx.x*4 + (threadIdx.x >> 6);
  const int lane = threadIdx.x & 63;
  const int idx = w*64 + lane;
  u32 v = (idx < NND) ? counts[idx] : 0u;
  #pragma unroll
  for (int off = 1; off < 64; off <<= 1) v += __shfl_xor(v, off);
  if (lane == 0 && w < NCHUNK) partial[w] = v;
}

// ---- parallel scan: stage 2 — exclusive scan of 784 partials (one block) ----
__global__ __launch_bounds__(1024, 1)
void scan_top_kernel(const u32* __restrict__ partial, u32* __restrict__ chunkoff)
{
  __shared__ u32 sh[1024];
  const int t = threadIdx.x;
  u32 p = (t < NCHUNK) ? partial[t] : 0u;
  sh[t] = p; __syncthreads();
  for (int off = 1; off < 1024; off <<= 1){
    u32 v = (t >= off) ? sh[t - off] : 0u;
    __syncthreads();
    sh[t] += v;
    __syncthreads();
  }
  chunkoff[t] = sh[t] - p;    // exclusive
}

// ---- parallel scan: stage 3 — wave-exclusive scan within chunk + offset ----
__global__ void scan_final_kernel(const u32* __restrict__ counts,
                                  const u32* __restrict__ chunkoff,
                                  u32* __restrict__ cursor)
{
  const int w = blockIdx.x*4 + (threadIdx.x >> 6);
  const int lane = threadIdx.x & 63;
  const int idx = w*64 + lane;
  u32 v = (idx < NND) ? counts[idx] : 0u;
  u32 x = v;
  #pragma unroll
  for (int off = 1; off < 64; off <<= 1){
    u32 y = __shfl_up(x, off);
    if (lane >= off) x += y;
  }
  if (idx < NND) cursor[idx] = x - v + chunkoff[w];
}

__global__ void scatter_kernel(const int* __restrict__ src, const int* __restrict__ dst,
                               const float* __restrict__ xyz, u32* __restrict__ cursor,
                               int* __restrict__ src_s, int* __restrict__ dst_s,
                               float* __restrict__ rad_s)
{
  int e = blockIdx.x * 256 + threadIdx.x;
  if (e >= NED) return;
  int s = src[e], d = dst[e];
  u32 p = atomicAdd(&cursor[d], 1u);
  float dx = xyz[3*s+0] - xyz[3*d+0];
  float dy = xyz[3*s+1] - xyz[3*d+1];
  float dz = xyz[3*s+2] - xyz[3*d+2];
  src_s[p] = s;
  dst_s[p] = d;
  rad_s[p] = dx*dx + dy*dy + dz*dz;
}

// ---------------- initial embedding: MFMA GEMM + in-register LN + erf GELU ----------------
__global__ __launch_bounds__(256, 2)
void embed_kernel(const float* __restrict__ X,
                  const us* __restrict__ W1T, const float* __restrict__ b1,
                  const float* __restrict__ g1, const float* __restrict__ e1,
                  const us* __restrict__ W2T, const float* __restrict__ b2,
                  const float* __restrict__ g2, const float* __restrict__ e2,
                  us* __restrict__ hb)
{
  __shared__ __align__(16) us lds_all[4*16*136];
  const int tid = threadIdx.x;
  const int wid = tid >> 6, lane = tid & 63;
  const int c = lane & 15, g = lane >> 4;
  const int tile = blockIdx.x*4 + wid;
  if (tile >= 3125) return;
  us* lds = lds_all + wid * 2176;
  const int nb = tile * 16;

  const float* xrow = X + (size_t)(nb + c)*64;
  bf16x8 a1[2];
  #pragma unroll
  for (int ks = 0; ks < 2; ks++){
    const int kl = ks*32 + 8*g;
    f32x4 f0 = *reinterpret_cast<const f32x4*>(xrow + kl);
    f32x4 f1 = *reinterpret_cast<const f32x4*>(xrow + kl + 4);
    bf16x8 a;
    #pragma unroll
    for (int j = 0; j < 4; j++){ a[j] = (__bf16)f0[j]; a[4+j] = (__bf16)f1[j]; }
    a1[ks] = a;
  }

  f32x4 acc[8];
  #pragma unroll
  for (int t = 0; t < 8; t++){
    float bv = b1[16*t + c];
    #pragma unroll
    for (int r = 0; r < 4; r++) acc[t][r] = bv;
  }
  const us* brow1 = W1T + c*64;
  #pragma unroll
  for (int ks = 0; ks < 2; ks++){
    const int kl = ks*32 + 8*g;
    #pragma unroll
    for (int t = 0; t < 8; t++){
      bf16x8 b = ldb8(brow1 + t*16*64 + kl);
      acc[t] = mfma16(a1[ks], b, acc[t]);
    }
  }

  #pragma unroll
  for (int r = 0; r < 4; r++){
    float s = 0.0f, q = 0.0f;
    #pragma unroll
    for (int t = 0; t < 8; t++){ s += acc[t][r]; q += acc[t][r]*acc[t][r]; }
    #pragma unroll
    for (int off = 1; off < 16; off <<= 1){ s += __shfl_xor(s, off); q += __shfl_xor(q, off); }
    float mean = s * (1.0f/128.0f);
    float var  = q * (1.0f/128.0f) - mean*mean;
    float inv  = rsqrtf(var + 1e-5f);
    #pragma unroll
    for (int t = 0; t < 8; t++){
      float xn = (acc[t][r] - mean)*inv*g1[16*t+c] + e1[16*t+c];
      acc[t][r] = gelu_f(xn);
    }
  }

  #pragma unroll
  for (int t = 0; t < 8; t++)
    #pragma unroll
    for (int r = 0; r < 4; r++)
      lds[(4*g+r)*136 + 16*t + c] = f2bfu(acc[t][r]);

  asm volatile("s_waitcnt lgkmcnt(0)" ::: "memory");

  f32x4 acc2[8];
  #pragma unroll
  for (int t = 0; t < 8; t++){
    float bv = b2[16*t + c];
    #pragma unroll
    for (int r = 0; r < 4; r++) acc2[t][r] = bv;
  }
  const us* brow2 = W2T + c*128;
  #pragma unroll
  for (int ks = 0; ks < 4; ks++){
    const int kl = ks*32 + 8*g;
    bf16x8 a = *reinterpret_cast<const bf16x8*>(lds + c*136 + kl);
    #pragma unroll
    for (int t = 0; t < 8; t++){
      bf16x8 b = ldb8(brow2 + t*16*128 + kl);
      acc2[t] = mfma16(a, b, acc2[t]);
    }
  }

  #pragma unroll
  for (int r = 0; r < 4; r++){
    float s = 0.0f, q = 0.0f;
    #pragma unroll
    for (int t = 0; t < 8; t++){ s += acc2[t][r]; q += acc2[t][r]*acc2[t][r]; }
    #pragma unroll
    for (int off = 1; off < 16; off <<= 1){ s += __shfl_xor(s, off); q += __shfl_xor(q, off); }
    float mean = s * (1.0f/128.0f);
    float var  = q * (1.0f/128.0f) - mean*mean;
    float inv  = rsqrtf(var + 1e-5f);
    #pragma unroll
    for (int t = 0; t < 8; t++){
      float xn = (acc2[t][r] - mean)*inv*g2[16*t+c] + e2[16*t+c];
      float y  = gelu_f(xn);
      hb[(size_t)(nb + 4*g + r)*CH + 16*t + c] = f2bfu(y);
    }
  }
}

// ---------------- per-node P/Q' precompute (per layer, bf16 out) ----------------
__global__ __launch_bounds__(256, 4)
void pq_kernel(const us* __restrict__ h, const us* __restrict__ W1T,
               const float* __restrict__ b1,
               us* __restrict__ P, us* __restrict__ Qb)
{
  const int tid = threadIdx.x;
  const int wid = tid >> 6, lane = tid & 63;
  const int c = lane & 15, g = lane >> 4;
  const int tile = blockIdx.x*4 + wid;
  if (tile >= 3125) return;
  const int nb = tile * 16;
  const us* arow = h + (size_t)(nb + c)*CH;

  bf16x8 a[4];
  #pragma unroll
  for (int ks = 0; ks < 4; ks++) a[ks] = ldb8(arow + ks*32 + 8*g);

  f32x4 accP[8], accQ[8];
  #pragma unroll
  for (int t = 0; t < 8; t++){
    float bq = b1[16*t + c];
    #pragma unroll
    for (int r = 0; r < 4; r++){ accP[t][r] = 0.0f; accQ[t][r] = bq; }
  }

  const us* brow = W1T + c*256;
  #pragma unroll
  for (int ks = 0; ks < 4; ks++){
    const int kl = ks*32 + 8*g;
    #pragma unroll
    for (int t = 0; t < 8; t++){
      bf16x8 bt = ldb8(brow + t*16*256 + kl);
      bf16x8 bb = ldb8(brow + t*16*256 + 128 + kl);
      accP[t] = mfma16(a[ks], bt, accP[t]);
      accQ[t] = mfma16(a[ks], bb, accQ[t]);
    }
  }

  #pragma unroll
  for (int t = 0; t < 8; t++)
    #pragma unroll
    for (int r = 0; r < 4; r++){
      size_t o = (size_t)(nb + 4*g + r)*CH + 16*t + c;
      P[o]  = f2bfu(accP[t][r]);
      Qb[o] = f2bfu(accQ[t][r]);
    }
}

// ---------------- fused edge kernel (per layer): 32 edges/wave, XCD swizzle ----------------
__global__ __launch_bounds__(256, 2)
void edge_kernel(const us* __restrict__ P, const us* __restrict__ Qb,
                 const float* __restrict__ radial,
                 const int* __restrict__ src, const int* __restrict__ dst,
                 const float* __restrict__ rw,
                 const us* __restrict__ W2T, const float* __restrict__ b2,
                 float* __restrict__ hn)
{
  const int tid = threadIdx.x;
  const int wid = tid >> 6, lane = tid & 63;
  const int c = lane & 15, g = lane >> 4;
  // bijective XCD swizzle: nwg=6250, q=781, r=2 -> consecutive tiles per XCD
  const int orig = blockIdx.x;
  const int xcd = orig & 7, idx8 = orig >> 3;
  const int blk = ((xcd < 2) ? xcd*782 : 2*782 + (xcd-2)*781) + idx8;
  const int eb = blk * 128 + wid * 32;

  int sA[2], dA[2]; float radA[2];
  #pragma unroll
  for (int m = 0; m < 2; m++){
    int e = eb + m*16 + c;
    sA[m] = src[e]; dA[m] = dst[e]; radA[m] = radial[e];
  }
  int dste[2][4]; int dnxt[2];
  #pragma unroll
  for (int m = 0; m < 2; m++){
    #pragma unroll
    for (int r = 0; r < 4; r++) dste[m][r] = dst[eb + m*16 + 4*g + r];
    dnxt[m] = (g < 3) ? dst[eb + m*16 + 4*g + 4] : -1;
  }

  float rwf[4][8];
  #pragma unroll
  for (int ks = 0; ks < 4; ks++){
    f32x4 r0 = *reinterpret_cast<const f32x4*>(rw + ks*32 + 8*g);
    f32x4 r1 = *reinterpret_cast<const f32x4*>(rw + ks*32 + 8*g + 4);
    #pragma unroll
    for (int j = 0; j < 4; j++){ rwf[ks][j] = r0[j]; rwf[ks][4+j] = r1[j]; }
  }

  bf16x8 afrag[2][4];
  #pragma unroll
  for (int m = 0; m < 2; m++){
    const us* Pr = P  + (size_t)sA[m]*CH;
    const us* Qr = Qb + (size_t)dA[m]*CH;
    const float rv = radA[m];
    #pragma unroll
    for (int ks = 0; ks < 4; ks++){
      const int kl = ks*32 + 8*g;
      bf16x8 pv = ldb8(Pr + kl);
      bf16x8 qv = ldb8(Qr + kl);
      bf16x8 a;
      #pragma unroll
      for (int j = 0; j < 8; j++){
        float x = (float)pv[j] + (float)qv[j] + rv*rwf[ks][j];
        a[j] = (__bf16)silu_f(x);
      }
      afrag[m][ks] = a;
    }
  }

  float b2v[8];
  #pragma unroll
  for (int t = 0; t < 8; t++) b2v[t] = b2[16*t+c];
  f32x4 acc2[2][8];
  #pragma unroll
  for (int m = 0; m < 2; m++)
    #pragma unroll
    for (int t = 0; t < 8; t++)
      #pragma unroll
      for (int r = 0; r < 4; r++)
        acc2[m][t][r] = b2v[t];

  const us* brow2 = W2T + c*128;
  #pragma unroll
  for (int ks = 0; ks < 4; ks++){
    const int kl = ks*32 + 8*g;
    bf16x8 a0 = afrag[0][ks];
    bf16x8 a1 = afrag[1][ks];
    #pragma unroll
    for (int t = 0; t < 8; t++){
      bf16x8 b = ldb8(brow2 + t*16*128 + kl);
      acc2[0][t] = mfma16(a0, b, acc2[0][t]);
      acc2[1][t] = mfma16(a1, b, acc2[1][t]);
    }
  }

  #pragma unroll
  for (int m = 0; m < 2; m++){
    const int d0 = dste[m][0], d1 = dste[m][1], d2 = dste[m][2], d3 = dste[m][3];
    const int dn = dnxt[m];
    const bool eq01 = (d0 == d1), eq12 = (d1 == d2), eq23 = (d2 == d3);
    const bool chain = eq01 && eq12 && eq23;
    const int pd3 = __shfl_up(d3, 16);
    const bool cont = (pd3 == d0);
    #pragma unroll
    for (int t = 0; t < 8; t++){
      float v0 = silu_f(acc2[m][t][0]);
      float v1 = silu_f(acc2[m][t][1]);
      float v2 = silu_f(acc2[m][t][2]);
      float v3 = silu_f(acc2[m][t][3]);
      v1 += eq01 ? v0 : 0.0f;
      v2 += eq12 ? v1 : 0.0f;
      v3 += eq23 ? v2 : 0.0f;
      float cin = 0.0f;
      float v3a = v3;
      #pragma unroll
      for (int s = 1; s <= 3; s++){
        float pv = __shfl_up(v3a, 16);
        cin = (g == s && cont) ? pv : cin;
        v3a = v3 + (chain ? cin : 0.0f);
      }
      const int col = 16*t + c;
      float c1 = eq01 ? cin : 0.0f;
      float c2 = (eq01 && eq12) ? cin : 0.0f;
      if (!eq01)    unsafeAtomicAdd(&hn[(size_t)d0*CH + col], v0 + cin);
      if (!eq12)    unsafeAtomicAdd(&hn[(size_t)d1*CH + col], v1 + c1);
      if (!eq23)    unsafeAtomicAdd(&hn[(size_t)d2*CH + col], v2 + c2);
      if (d3 != dn) unsafeAtomicAdd(&hn[(size_t)d3*CH + col], v3a);
    }
  }
}

// ---------------- fused node MLP (per layer) ----------------
__global__ __launch_bounds__(256, 4)
void node_kernel(const us* __restrict__ h, const float* __restrict__ hn,
                 const us* __restrict__ W1T, const float* __restrict__ b1,
                 const us* __restrict__ W2T, const float* __restrict__ b2,
                 float* __restrict__ hout, us* __restrict__ hb)
{
  __shared__ __align__(16) us lds_all[4*16*136];
  const int tid = threadIdx.x;
  const int wid = tid >> 6, lane = tid & 63;
  const int c = lane & 15, g = lane >> 4;
  const int tile = blockIdx.x*4 + wid;
  if (tile >= 3125) return;
  us* lds = lds_all + wid * 2176;
  const int nb = tile * 16;
  const us*    arow = h  + (size_t)(nb + c)*CH;
  const float* nrow = hn + (size_t)(nb + c)*CH;

  f32x4 acc[8];
  #pragma unroll
  for (int t = 0; t < 8; t++){
    float bv = b1[16*t+c];
    #pragma unroll
    for (int r = 0; r < 4; r++) acc[t][r] = bv;
  }
  const us* brow1 = W1T + c*256;
  #pragma unroll
  for (int ks = 0; ks < 8; ks++){
    const int kl = ks*32 + 8*g;
    bf16x8 a;
    if (ks < 4){
      a = ldb8(arow + kl);
    } else {
      const float* fp = nrow + (kl - 128);
      f32x4 f0 = *reinterpret_cast<const f32x4*>(fp);
      f32x4 f1 = *reinterpret_cast<const f32x4*>(fp + 4);
      #pragma unroll
      for (int i = 0; i < 4; i++){ a[i] = (__bf16)f0[i]; a[4+i] = (__bf16)f1[i]; }
    }
    #pragma unroll
    for (int t = 0; t < 8; t++){
      bf16x8 b = ldb8(brow1 + t*16*256 + kl);
      acc[t] = mfma16(a, b, acc[t]);
    }
  }

  #pragma unroll
  for (int t = 0; t < 8; t++)
    #pragma unroll
    for (int r = 0; r < 4; r++)
      lds[(4*g+r)*136 + 16*t + c] = f2bfu(silu_f(acc[t][r]));
  asm volatile("s_waitcnt lgkmcnt(0)" ::: "memory");

  f32x4 acc2[8];
  #pragma unroll
  for (int t = 0; t < 8; t++){
    float bv = b2[16*t+c];
    #pragma unroll
    for (int r = 0; r < 4; r++) acc2[t][r] = bv;
  }
  const us* brow2 = W2T + c*128;
  #pragma unroll
  for (int ks = 0; ks < 4; ks++){
    const int kl = ks*32 + 8*g;
    bf16x8 a = *reinterpret_cast<const bf16x8*>(lds + c*136 + kl);
    #pragma unroll
    for (int t = 0; t < 8; t++){
      bf16x8 b = ldb8(brow2 + t*16*128 + kl);
      acc2[t] = mfma16(a, b, acc2[t]);
    }
  }

  #pragma unroll
  for (int t = 0; t < 8; t++)
    #pragma unroll
    for (int r = 0; r < 4; r++){
      int node = nb + 4*g + r;
      int col  = 16*t + c;
      float v  = acc2[t][r];
      if (hout) hout[(size_t)node*CH + col] = v;
      if (hb)   hb[(size_t)node*CH + col] = f2bfu(v);
    }
}

// ---------------- host ----------------
extern "C" void kernel_launch(void* const* d_in, const int* in_sizes, int n_in,
                              void* d_out, int out_size, void* d_ws, size_t ws_size,
                              hipStream_t stream)
{
  const float* X      = (const float*)d_in[0];
  const float* xyz    = (const float*)d_in[1];
  const int*   src    = (const int*)  d_in[2];
  const int*   dst    = (const int*)  d_in[3];
  const float* W_in1  = (const float*)d_in[4];
  const float* b_in1  = (const float*)d_in[5];
  const float* g_in1  = (const float*)d_in[6];
  const float* be_in1 = (const float*)d_in[7];
  const float* W_in2  = (const float*)d_in[8];
  const float* b_in2  = (const float*)d_in[9];
  const float* g_in2  = (const float*)d_in[10];
  const float* be_in2 = (const float*)d_in[11];
  const float* We1    = (const float*)d_in[12];
  const float* be1    = (const float*)d_in[13];
  const float* We2    = (const float*)d_in[14];
  const float* be2    = (const float*)d_in[15];
  const float* Wn1    = (const float*)d_in[16];
  const float* bn1    = (const float*)d_in[17];
  const float* Wn2    = (const float*)d_in[18];
  const float* bn2    = (const float*)d_in[19];

  char* ws = (char*)d_ws;
  us*    h_bf  = (us*)ws;    ws += (size_t)NND*CH*2;   // 12.8 MB
  float* hn    = (float*)ws; ws += (size_t)NND*CH*4;   // 25.6 MB
  us*    Pbuf  = (us*)ws;    ws += (size_t)NND*CH*2;   // 12.8 MB
  us*    Qbuf  = (us*)ws;    ws += (size_t)NND*CH*2;   // 12.8 MB
  float* rad_s = (float*)ws; ws += (size_t)NED*4;      // 3.2 MB
  int*   src_s = (int*)ws;   ws += (size_t)NED*4;      // 3.2 MB
  int*   dst_s = (int*)ws;   ws += (size_t)NED*4;      // 3.2 MB
  us*    We1T  = (us*)ws;    ws += 2*128*256*2;
  us*    We2T  = (us*)ws;    ws += 2*128*128*2;
  us*    Wn1T  = (us*)ws;    ws += 2*128*256*2;
  us*    Wn2T  = (us*)ws;    ws += 2*128*128*2;
  us*    Wi1T  = (us*)ws;    ws += 128*64*2;
  us*    Wi2T  = (us*)ws;    ws += 128*128*2;
  float* rw    = (float*)ws; ws += 2*128*4;
  float* hout  = (float*)d_out;
  // sort scratch aliases hn (hn first written after sort completes)
  u32* counts   = (u32*)hn;
  u32* cursor   = (u32*)hn + NND;
  u32* partial  = (u32*)hn + 2*NND;
  u32* chunkoff = (u32*)hn + 2*NND + 1024;

  prep_kernel<<<256, 256, 0, stream>>>(We1, We2, Wn1, Wn2, W_in1, W_in2,
                                       We1T, We2T, Wn1T, Wn2T, Wi1T, Wi2T, rw);
  hipMemsetAsync(counts, 0, NND*sizeof(u32), stream);
  hist_kernel<<<3125, 256, 0, stream>>>(dst, counts);
  scan_part_kernel<<<196, 256, 0, stream>>>(counts, partial);
  scan_top_kernel<<<1, 1024, 0, stream>>>(partial, chunkoff);
  scan_final_kernel<<<196, 256, 0, stream>>>(counts, chunkoff, cursor);
  scatter_kernel<<<3125, 256, 0, stream>>>(src, dst, xyz, cursor, src_s, dst_s, rad_s);
  embed_kernel<<<782, 256, 0, stream>>>(X, Wi1T, b_in1, g_in1, be_in1,
                                        Wi2T, b_in2, g_in2, be_in2, h_bf);
  for (int l = 0; l < 2; l++){
    pq_kernel<<<782, 256, 0, stream>>>(h_bf, We1T + l*128*256, be1 + l*128, Pbuf, Qbuf);
    hipMemsetAsync(hn, 0, (size_t)NND*CH*4, stream);
    edge_kernel<<<6250, 256, 0, stream>>>(Pbuf, Qbuf, rad_s, src_s, dst_s,
        rw + l*128, We2T + l*128*128, be2 + l*128, hn);
    node_kernel<<<782, 256, 0, stream>>>(h_bf, hn,
        Wn1T + l*128*256, bn1 + l*128,
        Wn2T + l*128*128, bn2 + l*128,
        (l == 1) ? hout : nullptr, (l == 0) ? h_bf : nullptr);
  }
}

// Round 12
// 621.901 us; speedup vs baseline: 1.0257x; 1.0257x over previous
//
#include <hip/hip_runtime.h>
#include <stdint.h>

#define NND 50000
#define NED 800000
#define CH  128
#define NCHUNK 782   // ceil(NND/64)

typedef unsigned short us;
typedef unsigned int u32;
using bf16x8 = __attribute__((ext_vector_type(8))) __bf16;
using f32x4  = __attribute__((ext_vector_type(4))) float;

static __device__ __forceinline__ us f2bfu(float f){
  __bf16 b = (__bf16)f;
  return __builtin_bit_cast(us, b);
}
static __device__ __forceinline__ float silu_f(float x){
  return __fdividef(x, 1.0f + __expf(-x));
}
static __device__ __forceinline__ f32x4 mfma16(bf16x8 a, bf16x8 b, f32x4 c){
  return __builtin_amdgcn_mfma_f32_16x16x32_bf16(a, b, c, 0, 0, 0);
}
static __device__ __forceinline__ bf16x8 ldb8(const us* p){
  return *reinterpret_cast<const bf16x8*>(p);
}
static __device__ __forceinline__ float gelu_f(float x){
  return 0.5f*x*(1.0f + erff(x*0.70710678118654752f));
}

// ---------------- weight prep: transpose + bf16 cast ----------------
__global__ void prep_kernel(const float* __restrict__ We1, const float* __restrict__ We2,
                            const float* __restrict__ Wn1, const float* __restrict__ Wn2,
                            const float* __restrict__ Wi1, const float* __restrict__ Wi2,
                            us* __restrict__ We1T, us* __restrict__ We2T,
                            us* __restrict__ Wn1T, us* __restrict__ Wn2T,
                            us* __restrict__ Wi1T, us* __restrict__ Wi2T,
                            float* __restrict__ rw)
{
  int i = blockIdx.x * 256 + threadIdx.x;   // 0..65535
  {
    int l = i >> 15, j = (i >> 8) & 127, k = i & 255;
    We1T[i] = f2bfu(We1[(l*257 + k)*128 + j]);
    Wn1T[i] = f2bfu(Wn1[(l*256 + k)*128 + j]);
  }
  if (i < 32768) {
    int l = i >> 14, j = (i >> 7) & 127, k = i & 127;
    We2T[i] = f2bfu(We2[(l*128 + k)*128 + j]);
    Wn2T[i] = f2bfu(Wn2[(l*128 + k)*128 + j]);
  }
  if (i < 8192) {
    int j = i >> 6, k = i & 63;
    Wi1T[i] = f2bfu(Wi1[k*128 + j]);
  }
  if (i < 16384) {
    int j = i >> 7, k = i & 127;
    Wi2T[i] = f2bfu(Wi2[k*128 + j]);
  }
  if (i < 256) {
    int l = i >> 7, j = i & 127;
    rw[i] = We1[(l*257 + 256)*128 + j];
  }
}

// ---------------- counting sort by dst ----------------
__global__ void hist_kernel(const int* __restrict__ dst, u32* __restrict__ counts)
{
  int e = blockIdx.x * 256 + threadIdx.x;
  if (e < NED) atomicAdd(&counts[dst[e]], 1u);
}

__global__ void scan_part_kernel(const u32* __restrict__ counts, u32* __restrict__ partial)
{
  const int w = blockIdx.x*4 + (threadIdx.x >> 6);
  const int lane = threadIdx.x & 63;
  const int idx = w*64 + lane;
  u32 v = (idx < NND) ? counts[idx] : 0u;
  #pragma unroll
  for (int off = 1; off < 64; off <<= 1) v += __shfl_xor(v, off);
  if (lane == 0 && w < NCHUNK) partial[w] = v;
}

__global__ __launch_bounds__(1024, 1)
void scan_top_kernel(const u32* __restrict__ partial, u32* __restrict__ chunkoff)
{
  __shared__ u32 sh[1024];
  const int t = threadIdx.x;
  u32 p = (t < NCHUNK) ? partial[t] : 0u;
  sh[t] = p; __syncthreads();
  for (int off = 1; off < 1024; off <<= 1){
    u32 v = (t >= off) ? sh[t - off] : 0u;
    __syncthreads();
    sh[t] += v;
    __syncthreads();
  }
  chunkoff[t] = sh[t] - p;    // exclusive
}

__global__ void scan_final_kernel(const u32* __restrict__ counts,
                                  const u32* __restrict__ chunkoff,
                                  u32* __restrict__ cursor)
{
  const int w = blockIdx.x*4 + (threadIdx.x >> 6);
  const int lane = threadIdx.x & 63;
  const int idx = w*64 + lane;
  u32 v = (idx < NND) ? counts[idx] : 0u;
  u32 x = v;
  #pragma unroll
  for (int off = 1; off < 64; off <<= 1){
    u32 y = __shfl_up(x, off);
    if (lane >= off) x += y;
  }
  if (idx < NND) cursor[idx] = x - v + chunkoff[w];
}

__global__ void scatter_kernel(const int* __restrict__ src, const int* __restrict__ dst,
                               const float* __restrict__ xyz, u32* __restrict__ cursor,
                               int* __restrict__ src_s, int* __restrict__ dst_s,
                               float* __restrict__ rad_s)
{
  int e = blockIdx.x * 256 + threadIdx.x;
  if (e >= NED) return;
  int s = src[e], d = dst[e];
  u32 p = atomicAdd(&cursor[d], 1u);
  float dx = xyz[3*s+0] - xyz[3*d+0];
  float dy = xyz[3*s+1] - xyz[3*d+1];
  float dz = xyz[3*s+2] - xyz[3*d+2];
  src_s[p] = s;
  dst_s[p] = d;
  rad_s[p] = dx*dx + dy*dy + dz*dz;
}

// ---------------- initial embedding + fused layer-0 P/Q ----------------
// Per-wave LDS = two disjoint 2176-us halves: half0 = GEMM staging,
// half1 = h restage for P/Q (never overwrite a region after reading it).
__global__ __launch_bounds__(256, 2)
void embed_kernel(const float* __restrict__ X,
                  const us* __restrict__ W1T, const float* __restrict__ b1,
                  const float* __restrict__ g1, const float* __restrict__ e1,
                  const us* __restrict__ W2T, const float* __restrict__ b2,
                  const float* __restrict__ g2, const float* __restrict__ e2,
                  us* __restrict__ hb,
                  const us* __restrict__ We1T0, const float* __restrict__ be10,
                  us* __restrict__ P, us* __restrict__ Qb)
{
  __shared__ __align__(16) us lds_all[4*2*2176];
  const int tid = threadIdx.x;
  const int wid = tid >> 6, lane = tid & 63;
  const int c = lane & 15, g = lane >> 4;
  const int tile = blockIdx.x*4 + wid;
  if (tile >= 3125) return;
  us* lds  = lds_all + wid * 4352;
  us* lds2 = lds + 2176;
  const int nb = tile * 16;

  const float* xrow = X + (size_t)(nb + c)*64;
  bf16x8 a1[2];
  #pragma unroll
  for (int ks = 0; ks < 2; ks++){
    const int kl = ks*32 + 8*g;
    f32x4 f0 = *reinterpret_cast<const f32x4*>(xrow + kl);
    f32x4 f1 = *reinterpret_cast<const f32x4*>(xrow + kl + 4);
    bf16x8 a;
    #pragma unroll
    for (int j = 0; j < 4; j++){ a[j] = (__bf16)f0[j]; a[4+j] = (__bf16)f1[j]; }
    a1[ks] = a;
  }

  f32x4 acc[8];
  #pragma unroll
  for (int t = 0; t < 8; t++){
    float bv = b1[16*t + c];
    #pragma unroll
    for (int r = 0; r < 4; r++) acc[t][r] = bv;
  }
  const us* brow1 = W1T + c*64;
  #pragma unroll
  for (int ks = 0; ks < 2; ks++){
    const int kl = ks*32 + 8*g;
    #pragma unroll
    for (int t = 0; t < 8; t++){
      bf16x8 b = ldb8(brow1 + t*16*64 + kl);
      acc[t] = mfma16(a1[ks], b, acc[t]);
    }
  }

  #pragma unroll
  for (int r = 0; r < 4; r++){
    float s = 0.0f, q = 0.0f;
    #pragma unroll
    for (int t = 0; t < 8; t++){ s += acc[t][r]; q += acc[t][r]*acc[t][r]; }
    #pragma unroll
    for (int off = 1; off < 16; off <<= 1){ s += __shfl_xor(s, off); q += __shfl_xor(q, off); }
    float mean = s * (1.0f/128.0f);
    float var  = q * (1.0f/128.0f) - mean*mean;
    float inv  = rsqrtf(var + 1e-5f);
    #pragma unroll
    for (int t = 0; t < 8; t++){
      float xn = (acc[t][r] - mean)*inv*g1[16*t+c] + e1[16*t+c];
      acc[t][r] = gelu_f(xn);
    }
  }

  #pragma unroll
  for (int t = 0; t < 8; t++)
    #pragma unroll
    for (int r = 0; r < 4; r++)
      lds[(4*g+r)*136 + 16*t + c] = f2bfu(acc[t][r]);

  asm volatile("s_waitcnt lgkmcnt(0)" ::: "memory");

  f32x4 acc2[8];
  #pragma unroll
  for (int t = 0; t < 8; t++){
    float bv = b2[16*t + c];
    #pragma unroll
    for (int r = 0; r < 4; r++) acc2[t][r] = bv;
  }
  const us* brow2 = W2T + c*128;
  #pragma unroll
  for (int ks = 0; ks < 4; ks++){
    const int kl = ks*32 + 8*g;
    bf16x8 a = *reinterpret_cast<const bf16x8*>(lds + c*136 + kl);
    #pragma unroll
    for (int t = 0; t < 8; t++){
      bf16x8 b = ldb8(brow2 + t*16*128 + kl);
      acc2[t] = mfma16(a, b, acc2[t]);
    }
  }

  #pragma unroll
  for (int r = 0; r < 4; r++){
    float s = 0.0f, q = 0.0f;
    #pragma unroll
    for (int t = 0; t < 8; t++){ s += acc2[t][r]; q += acc2[t][r]*acc2[t][r]; }
    #pragma unroll
    for (int off = 1; off < 16; off <<= 1){ s += __shfl_xor(s, off); q += __shfl_xor(q, off); }
    float mean = s * (1.0f/128.0f);
    float var  = q * (1.0f/128.0f) - mean*mean;
    float inv  = rsqrtf(var + 1e-5f);
    #pragma unroll
    for (int t = 0; t < 8; t++){
      float xn = (acc2[t][r] - mean)*inv*g2[16*t+c] + e2[16*t+c];
      acc2[t][r] = gelu_f(xn);
    }
  }

  // write h to global + restage in DISJOINT half (lds2), then layer-0 P/Q
  #pragma unroll
  for (int t = 0; t < 8; t++)
    #pragma unroll
    for (int r = 0; r < 4; r++){
      us hv = f2bfu(acc2[t][r]);
      hb[(size_t)(nb + 4*g + r)*CH + 16*t + c] = hv;
      lds2[(4*g+r)*136 + 16*t + c] = hv;
    }
  asm volatile("s_waitcnt lgkmcnt(0)" ::: "memory");

  bf16x8 af[4];
  #pragma unroll
  for (int ks = 0; ks < 4; ks++)
    af[ks] = *reinterpret_cast<const bf16x8*>(lds2 + c*136 + ks*32 + 8*g);

  f32x4 accX[8];
  #pragma unroll
  for (int t = 0; t < 8; t++)
    #pragma unroll
    for (int r = 0; r < 4; r++) accX[t][r] = 0.0f;
  const us* brow = We1T0 + c*256;
  #pragma unroll
  for (int ks = 0; ks < 4; ks++){
    const int kl = ks*32 + 8*g;
    #pragma unroll
    for (int t = 0; t < 8; t++){
      bf16x8 b = ldb8(brow + t*16*256 + kl);
      accX[t] = mfma16(af[ks], b, accX[t]);
    }
  }
  #pragma unroll
  for (int t = 0; t < 8; t++)
    #pragma unroll
    for (int r = 0; r < 4; r++)
      P[(size_t)(nb + 4*g + r)*CH + 16*t + c] = f2bfu(accX[t][r]);

  #pragma unroll
  for (int t = 0; t < 8; t++){
    float bq = be10[16*t + c];
    #pragma unroll
    for (int r = 0; r < 4; r++) accX[t][r] = bq;
  }
  #pragma unroll
  for (int ks = 0; ks < 4; ks++){
    const int kl = ks*32 + 8*g;
    #pragma unroll
    for (int t = 0; t < 8; t++){
      bf16x8 b = ldb8(brow + t*16*256 + 128 + kl);
      accX[t] = mfma16(af[ks], b, accX[t]);
    }
  }
  #pragma unroll
  for (int t = 0; t < 8; t++)
    #pragma unroll
    for (int r = 0; r < 4; r++)
      Qb[(size_t)(nb + 4*g + r)*CH + 16*t + c] = f2bfu(accX[t][r]);
}

// ---------------- fused edge kernel (per layer): 32 edges/wave, XCD swizzle ----------------
__global__ __launch_bounds__(256, 2)
void edge_kernel(const us* __restrict__ P, const us* __restrict__ Qb,
                 const float* __restrict__ radial,
                 const int* __restrict__ src, const int* __restrict__ dst,
                 const float* __restrict__ rw,
                 const us* __restrict__ W2T, const float* __restrict__ b2,
                 float* __restrict__ hn)
{
  const int tid = threadIdx.x;
  const int wid = tid >> 6, lane = tid & 63;
  const int c = lane & 15, g = lane >> 4;
  const int orig = blockIdx.x;
  const int xcd = orig & 7, idx8 = orig >> 3;
  const int blk = ((xcd < 2) ? xcd*782 : 2*782 + (xcd-2)*781) + idx8;
  const int eb = blk * 128 + wid * 32;

  int sA[2], dA[2]; float radA[2];
  #pragma unroll
  for (int m = 0; m < 2; m++){
    int e = eb + m*16 + c;
    sA[m] = src[e]; dA[m] = dst[e]; radA[m] = radial[e];
  }
  int dste[2][4]; int dnxt[2];
  #pragma unroll
  for (int m = 0; m < 2; m++){
    #pragma unroll
    for (int r = 0; r < 4; r++) dste[m][r] = dst[eb + m*16 + 4*g + r];
    dnxt[m] = (g < 3) ? dst[eb + m*16 + 4*g + 4] : -1;
  }

  float rwf[4][8];
  #pragma unroll
  for (int ks = 0; ks < 4; ks++){
    f32x4 r0 = *reinterpret_cast<const f32x4*>(rw + ks*32 + 8*g);
    f32x4 r1 = *reinterpret_cast<const f32x4*>(rw + ks*32 + 8*g + 4);
    #pragma unroll
    for (int j = 0; j < 4; j++){ rwf[ks][j] = r0[j]; rwf[ks][4+j] = r1[j]; }
  }

  bf16x8 afrag[2][4];
  #pragma unroll
  for (int m = 0; m < 2; m++){
    const us* Pr = P  + (size_t)sA[m]*CH;
    const us* Qr = Qb + (size_t)dA[m]*CH;
    const float rv = radA[m];
    #pragma unroll
    for (int ks = 0; ks < 4; ks++){
      const int kl = ks*32 + 8*g;
      bf16x8 pv = ldb8(Pr + kl);
      bf16x8 qv = ldb8(Qr + kl);
      bf16x8 a;
      #pragma unroll
      for (int j = 0; j < 8; j++){
        float x = (float)pv[j] + (float)qv[j] + rv*rwf[ks][j];
        a[j] = (__bf16)silu_f(x);
      }
      afrag[m][ks] = a;
    }
  }

  float b2v[8];
  #pragma unroll
  for (int t = 0; t < 8; t++) b2v[t] = b2[16*t+c];
  f32x4 acc2[2][8];
  #pragma unroll
  for (int m = 0; m < 2; m++)
    #pragma unroll
    for (int t = 0; t < 8; t++)
      #pragma unroll
      for (int r = 0; r < 4; r++)
        acc2[m][t][r] = b2v[t];

  const us* brow2 = W2T + c*128;
  #pragma unroll
  for (int ks = 0; ks < 4; ks++){
    const int kl = ks*32 + 8*g;
    bf16x8 a0 = afrag[0][ks];
    bf16x8 a1 = afrag[1][ks];
    #pragma unroll
    for (int t = 0; t < 8; t++){
      bf16x8 b = ldb8(brow2 + t*16*128 + kl);
      acc2[0][t] = mfma16(a0, b, acc2[0][t]);
      acc2[1][t] = mfma16(a1, b, acc2[1][t]);
    }
  }

  #pragma unroll
  for (int m = 0; m < 2; m++){
    const int d0 = dste[m][0], d1 = dste[m][1], d2 = dste[m][2], d3 = dste[m][3];
    const int dn = dnxt[m];
    const bool eq01 = (d0 == d1), eq12 = (d1 == d2), eq23 = (d2 == d3);
    const bool chain = eq01 && eq12 && eq23;
    const int pd3 = __shfl_up(d3, 16);
    const bool cont = (pd3 == d0);
    #pragma unroll
    for (int t = 0; t < 8; t++){
      float v0 = silu_f(acc2[m][t][0]);
      float v1 = silu_f(acc2[m][t][1]);
      float v2 = silu_f(acc2[m][t][2]);
      float v3 = silu_f(acc2[m][t][3]);
      v1 += eq01 ? v0 : 0.0f;
      v2 += eq12 ? v1 : 0.0f;
      v3 += eq23 ? v2 : 0.0f;
      float cin = 0.0f;
      float v3a = v3;
      #pragma unroll
      for (int s = 1; s <= 3; s++){
        float pv = __shfl_up(v3a, 16);
        cin = (g == s && cont) ? pv : cin;
        v3a = v3 + (chain ? cin : 0.0f);
      }
      const int col = 16*t + c;
      float c1 = eq01 ? cin : 0.0f;
      float c2 = (eq01 && eq12) ? cin : 0.0f;
      if (!eq01)    unsafeAtomicAdd(&hn[(size_t)d0*CH + col], v0 + cin);
      if (!eq12)    unsafeAtomicAdd(&hn[(size_t)d1*CH + col], v1 + c1);
      if (!eq23)    unsafeAtomicAdd(&hn[(size_t)d2*CH + col], v2 + c2);
      if (d3 != dn) unsafeAtomicAdd(&hn[(size_t)d3*CH + col], v3a);
    }
  }
}

// ---------------- node MLP layer 0 + fused layer-1 P/Q ----------------
__global__ __launch_bounds__(256, 3)
void node_pq_kernel(const us* __restrict__ h, const float* __restrict__ hn,
                    const us* __restrict__ W1T, const float* __restrict__ b1,
                    const us* __restrict__ W2T, const float* __restrict__ b2,
                    us* __restrict__ hb,
                    const us* __restrict__ We1T1, const float* __restrict__ be11,
                    us* __restrict__ P, us* __restrict__ Qb)
{
  __shared__ __align__(16) us lds_all[4*2*2176];
  const int tid = threadIdx.x;
  const int wid = tid >> 6, lane = tid & 63;
  const int c = lane & 15, g = lane >> 4;
  const int tile = blockIdx.x*4 + wid;
  if (tile >= 3125) return;
  us* lds  = lds_all + wid * 4352;
  us* lds2 = lds + 2176;
  const int nb = tile * 16;
  const us*    arow = h  + (size_t)(nb + c)*CH;
  const float* nrow = hn + (size_t)(nb + c)*CH;

  f32x4 acc[8];
  #pragma unroll
  for (int t = 0; t < 8; t++){
    float bv = b1[16*t+c];
    #pragma unroll
    for (int r = 0; r < 4; r++) acc[t][r] = bv;
  }
  const us* brow1 = W1T + c*256;
  #pragma unroll
  for (int ks = 0; ks < 8; ks++){
    const int kl = ks*32 + 8*g;
    bf16x8 a;
    if (ks < 4){
      a = ldb8(arow + kl);
    } else {
      const float* fp = nrow + (kl - 128);
      f32x4 f0 = *reinterpret_cast<const f32x4*>(fp);
      f32x4 f1 = *reinterpret_cast<const f32x4*>(fp + 4);
      #pragma unroll
      for (int i = 0; i < 4; i++){ a[i] = (__bf16)f0[i]; a[4+i] = (__bf16)f1[i]; }
    }
    #pragma unroll
    for (int t = 0; t < 8; t++){
      bf16x8 b = ldb8(brow1 + t*16*256 + kl);
      acc[t] = mfma16(a, b, acc[t]);
    }
  }

  #pragma unroll
  for (int t = 0; t < 8; t++)
    #pragma unroll
    for (int r = 0; r < 4; r++)
      lds[(4*g+r)*136 + 16*t + c] = f2bfu(silu_f(acc[t][r]));
  asm volatile("s_waitcnt lgkmcnt(0)" ::: "memory");

  f32x4 acc2[8];
  #pragma unroll
  for (int t = 0; t < 8; t++){
    float bv = b2[16*t+c];
    #pragma unroll
    for (int r = 0; r < 4; r++) acc2[t][r] = bv;
  }
  const us* brow2 = W2T + c*128;
  #pragma unroll
  for (int ks = 0; ks < 4; ks++){
    const int kl = ks*32 + 8*g;
    bf16x8 a = *reinterpret_cast<const bf16x8*>(lds + c*136 + kl);
    #pragma unroll
    for (int t = 0; t < 8; t++){
      bf16x8 b = ldb8(brow2 + t*16*128 + kl);
      acc2[t] = mfma16(a, b, acc2[t]);
    }
  }

  // write h1 to global + restage in DISJOINT half (lds2), then layer-1 P/Q
  #pragma unroll
  for (int t = 0; t < 8; t++)
    #pragma unroll
    for (int r = 0; r < 4; r++){
      us hv = f2bfu(acc2[t][r]);
      hb[(size_t)(nb + 4*g + r)*CH + 16*t + c] = hv;
      lds2[(4*g+r)*136 + 16*t + c] = hv;
    }
  asm volatile("s_waitcnt lgkmcnt(0)" ::: "memory");

  bf16x8 af[4];
  #pragma unroll
  for (int ks = 0; ks < 4; ks++)
    af[ks] = *reinterpret_cast<const bf16x8*>(lds2 + c*136 + ks*32 + 8*g);

  f32x4 accX[8];
  #pragma unroll
  for (int t = 0; t < 8; t++)
    #pragma unroll
    for (int r = 0; r < 4; r++) accX[t][r] = 0.0f;
  const us* brow = We1T1 + c*256;
  #pragma unroll
  for (int ks = 0; ks < 4; ks++){
    const int kl = ks*32 + 8*g;
    #pragma unroll
    for (int t = 0; t < 8; t++){
      bf16x8 b = ldb8(brow + t*16*256 + kl);
      accX[t] = mfma16(af[ks], b, accX[t]);
    }
  }
  #pragma unroll
  for (int t = 0; t < 8; t++)
    #pragma unroll
    for (int r = 0; r < 4; r++)
      P[(size_t)(nb + 4*g + r)*CH + 16*t + c] = f2bfu(accX[t][r]);

  #pragma unroll
  for (int t = 0; t < 8; t++){
    float bq = be11[16*t + c];
    #pragma unroll
    for (int r = 0; r < 4; r++) accX[t][r] = bq;
  }
  #pragma unroll
  for (int ks = 0; ks < 4; ks++){
    const int kl = ks*32 + 8*g;
    #pragma unroll
    for (int t = 0; t < 8; t++){
      bf16x8 b = ldb8(brow + t*16*256 + 128 + kl);
      accX[t] = mfma16(af[ks], b, accX[t]);
    }
  }
  #pragma unroll
  for (int t = 0; t < 8; t++)
    #pragma unroll
    for (int r = 0; r < 4; r++)
      Qb[(size_t)(nb + 4*g + r)*CH + 16*t + c] = f2bfu(accX[t][r]);
}

// ---------------- node MLP layer 1 (final, fp32 out only) ----------------
__global__ __launch_bounds__(256, 4)
void node_kernel(const us* __restrict__ h, const float* __restrict__ hn,
                 const us* __restrict__ W1T, const float* __restrict__ b1,
                 const us* __restrict__ W2T, const float* __restrict__ b2,
                 float* __restrict__ hout)
{
  __shared__ __align__(16) us lds_all[4*16*136];
  const int tid = threadIdx.x;
  const int wid = tid >> 6, lane = tid & 63;
  const int c = lane & 15, g = lane >> 4;
  const int tile = blockIdx.x*4 + wid;
  if (tile >= 3125) return;
  us* lds = lds_all + wid * 2176;
  const int nb = tile * 16;
  const us*    arow = h  + (size_t)(nb + c)*CH;
  const float* nrow = hn + (size_t)(nb + c)*CH;

  f32x4 acc[8];
  #pragma unroll
  for (int t = 0; t < 8; t++){
    float bv = b1[16*t+c];
    #pragma unroll
    for (int r = 0; r < 4; r++) acc[t][r] = bv;
  }
  const us* brow1 = W1T + c*256;
  #pragma unroll
  for (int ks = 0; ks < 8; ks++){
    const int kl = ks*32 + 8*g;
    bf16x8 a;
    if (ks < 4){
      a = ldb8(arow + kl);
    } else {
      const float* fp = nrow + (kl - 128);
      f32x4 f0 = *reinterpret_cast<const f32x4*>(fp);
      f32x4 f1 = *reinterpret_cast<const f32x4*>(fp + 4);
      #pragma unroll
      for (int i = 0; i < 4; i++){ a[i] = (__bf16)f0[i]; a[4+i] = (__bf16)f1[i]; }
    }
    #pragma unroll
    for (int t = 0; t < 8; t++){
      bf16x8 b = ldb8(brow1 + t*16*256 + kl);
      acc[t] = mfma16(a, b, acc[t]);
    }
  }

  #pragma unroll
  for (int t = 0; t < 8; t++)
    #pragma unroll
    for (int r = 0; r < 4; r++)
      lds[(4*g+r)*136 + 16*t + c] = f2bfu(silu_f(acc[t][r]));
  asm volatile("s_waitcnt lgkmcnt(0)" ::: "memory");

  f32x4 acc2[8];
  #pragma unroll
  for (int t = 0; t < 8; t++){
    float bv = b2[16*t+c];
    #pragma unroll
    for (int r = 0; r < 4; r++) acc2[t][r] = bv;
  }
  const us* brow2 = W2T + c*128;
  #pragma unroll
  for (int ks = 0; ks < 4; ks++){
    const int kl = ks*32 + 8*g;
    bf16x8 a = *reinterpret_cast<const bf16x8*>(lds + c*136 + kl);
    #pragma unroll
    for (int t = 0; t < 8; t++){
      bf16x8 b = ldb8(brow2 + t*16*128 + kl);
      acc2[t] = mfma16(a, b, acc2[t]);
    }
  }

  #pragma unroll
  for (int t = 0; t < 8; t++)
    #pragma unroll
    for (int r = 0; r < 4; r++)
      hout[(size_t)(nb + 4*g + r)*CH + 16*t + c] = acc2[t][r];
}

// ---------------- host ----------------
extern "C" void kernel_launch(void* const* d_in, const int* in_sizes, int n_in,
                              void* d_out, int out_size, void* d_ws, size_t ws_size,
                              hipStream_t stream)
{
  const float* X      = (const float*)d_in[0];
  const float* xyz    = (const float*)d_in[1];
  const int*   src    = (const int*)  d_in[2];
  const int*   dst    = (const int*)  d_in[3];
  const float* W_in1  = (const float*)d_in[4];
  const float* b_in1  = (const float*)d_in[5];
  const float* g_in1  = (const float*)d_in[6];
  const float* be_in1 = (const float*)d_in[7];
  const float* W_in2  = (const float*)d_in[8];
  const float* b_in2  = (const float*)d_in[9];
  const float* g_in2  = (const float*)d_in[10];
  const float* be_in2 = (const float*)d_in[11];
  const float* We1    = (const float*)d_in[12];
  const float* be1    = (const float*)d_in[13];
  const float* We2    = (const float*)d_in[14];
  const float* be2    = (const float*)d_in[15];
  const float* Wn1    = (const float*)d_in[16];
  const float* bn1    = (const float*)d_in[17];
  const float* Wn2    = (const float*)d_in[18];
  const float* bn2    = (const float*)d_in[19];

  char* ws = (char*)d_ws;
  us*    h_bf  = (us*)ws;    ws += (size_t)NND*CH*2;   // 12.8 MB
  float* hn    = (float*)ws; ws += (size_t)NND*CH*4;   // 25.6 MB
  us*    Pbuf  = (us*)ws;    ws += (size_t)NND*CH*2;   // 12.8 MB
  us*    Qbuf  = (us*)ws;    ws += (size_t)NND*CH*2;   // 12.8 MB
  float* rad_s = (float*)ws; ws += (size_t)NED*4;      // 3.2 MB
  int*   src_s = (int*)ws;   ws += (size_t)NED*4;      // 3.2 MB
  int*   dst_s = (int*)ws;   ws += (size_t)NED*4;      // 3.2 MB
  us*    We1T  = (us*)ws;    ws += 2*128*256*2;
  us*    We2T  = (us*)ws;    ws += 2*128*128*2;
  us*    Wn1T  = (us*)ws;    ws += 2*128*256*2;
  us*    Wn2T  = (us*)ws;    ws += 2*128*128*2;
  us*    Wi1T  = (us*)ws;    ws += 128*64*2;
  us*    Wi2T  = (us*)ws;    ws += 128*128*2;
  float* rw    = (float*)ws; ws += 2*128*4;
  float* hout  = (float*)d_out;
  // sort scratch aliases hn (hn first written after sort completes)
  u32* counts   = (u32*)hn;
  u32* cursor   = (u32*)hn + NND;
  u32* partial  = (u32*)hn + 2*NND;
  u32* chunkoff = (u32*)hn + 2*NND + 1024;

  prep_kernel<<<256, 256, 0, stream>>>(We1, We2, Wn1, Wn2, W_in1, W_in2,
                                       We1T, We2T, Wn1T, Wn2T, Wi1T, Wi2T, rw);
  hipMemsetAsync(counts, 0, NND*sizeof(u32), stream);
  hist_kernel<<<3125, 256, 0, stream>>>(dst, counts);
  scan_part_kernel<<<196, 256, 0, stream>>>(counts, partial);
  scan_top_kernel<<<1, 1024, 0, stream>>>(partial, chunkoff);
  scan_final_kernel<<<196, 256, 0, stream>>>(counts, chunkoff, cursor);
  scatter_kernel<<<3125, 256, 0, stream>>>(src, dst, xyz, cursor, src_s, dst_s, rad_s);
  embed_kernel<<<782, 256, 0, stream>>>(X, Wi1T, b_in1, g_in1, be_in1,
                                        Wi2T, b_in2, g_in2, be_in2, h_bf,
                                        We1T + 0*128*256, be1 + 0*128, Pbuf, Qbuf);
  // layer 0
  hipMemsetAsync(hn, 0, (size_t)NND*CH*4, stream);
  edge_kernel<<<6250, 256, 0, stream>>>(Pbuf, Qbuf, rad_s, src_s, dst_s,
      rw + 0*128, We2T + 0*128*128, be2 + 0*128, hn);
  node_pq_kernel<<<782, 256, 0, stream>>>(h_bf, hn,
      Wn1T + 0*128*256, bn1 + 0*128, Wn2T + 0*128*128, bn2 + 0*128,
      h_bf, We1T + 1*128*256, be1 + 1*128, Pbuf, Qbuf);
  // layer 1
  hipMemsetAsync(hn, 0, (size_t)NND*CH*4, stream);
  edge_kernel<<<6250, 256, 0, stream>>>(Pbuf, Qbuf, rad_s, src_s, dst_s,
      rw + 1*128, We2T + 1*128*128, be2 + 1*128, hn);
  node_kernel<<<782, 256, 0, stream>>>(h_bf, hn,
      Wn1T + 1*128*256, bn1 + 1*128, Wn2T + 1*128*128, bn2 + 1*128, hout);
}